// Round 6
// baseline (4158.627 us; speedup 1.0000x reference)
//
#include <hip/hip_runtime.h>

#define B_  64
#define S_  256
#define H_  768
#define H4_ 3072
#define D2_ 1536
#define SEG 64
#define USZ (64*2304)

using u16 = unsigned short;
using u32 = unsigned int;
using u64 = unsigned long long;
typedef __attribute__((ext_vector_type(8))) short bf16x8;
typedef __attribute__((ext_vector_type(4))) float f32x4;
typedef __attribute__((ext_vector_type(4))) unsigned int u32x4;

#define DEV __device__ __forceinline__

DEV float bf2f(u16 u){ union{u32 i; float f;} c; c.i = ((u32)u)<<16; return c.f; }
DEV u16 f2bf(float f){ union{float f; u32 i;} c; c.f = f; return (u16)((c.i + 0x7FFFu + ((c.i>>16)&1u)) >> 16); }
DEV float sigm(float x){ return 1.f/(1.f + __expf(-x)); }
DEV float tanh_(float x){ return 2.f/(1.f + __expf(-2.f*x)) - 1.f; }

// agent-scope publication / flag ops
DEV void astore32(u16* p, u32 v){ __hip_atomic_store((u32*)p, v, __ATOMIC_RELAXED, __HIP_MEMORY_SCOPE_AGENT); }
DEV int afload(const int* p){ return __hip_atomic_load(p, __ATOMIC_RELAXED, __HIP_MEMORY_SCOPE_AGENT); }

DEV f32x4 mfma16(bf16x8 a, bf16x8 b, f32x4 c){
  return __builtin_amdgcn_mfma_f32_16x16x32_bf16(a, b, c, 0, 0, 0);
}

// 96B (48 u16) coherent staging load: 6 x dwordx4 bypassing L1/L2 (sc0 sc1 ->
// LLC-direct), one vmcnt drain. Early-clobber outputs: loads write before the
// last use of the address pair.
DEV void llc_load96(const u16* p, u32x4& a0, u32x4& a1, u32x4& a2,
                    u32x4& a3, u32x4& a4, u32x4& a5){
  asm volatile(
    "global_load_dwordx4 %0, %6, off sc0 sc1\n\t"
    "global_load_dwordx4 %1, %6, off offset:16 sc0 sc1\n\t"
    "global_load_dwordx4 %2, %6, off offset:32 sc0 sc1\n\t"
    "global_load_dwordx4 %3, %6, off offset:48 sc0 sc1\n\t"
    "global_load_dwordx4 %4, %6, off offset:64 sc0 sc1\n\t"
    "global_load_dwordx4 %5, %6, off offset:80 sc0 sc1\n\t"
    "s_waitcnt vmcnt(0)"
    : "=&v"(a0), "=&v"(a1), "=&v"(a2), "=&v"(a3), "=&v"(a4), "=&v"(a5)
    : "v"(p));
}
DEV void stage48llc(u16* dst, const u16* src){
  u32x4 a0,a1,a2,a3,a4,a5;
  llc_load96(src, a0,a1,a2,a3,a4,a5);
  *(u32x4*)(dst)    = a0; *(u32x4*)(dst+8)  = a1;
  *(u32x4*)(dst+16) = a2; *(u32x4*)(dst+24) = a3;
  *(u32x4*)(dst+32) = a4; *(u32x4*)(dst+40) = a5;
}
DEV void stage48llcz(u16* dst, const u16* src, bool keep){
  u32x4 a0,a1,a2,a3,a4,a5;
  llc_load96(src, a0,a1,a2,a3,a4,a5);
  const u32x4 z = {0u,0u,0u,0u};
  if (!keep){ a0=z; a1=z; a2=z; a3=z; a4=z; a5=z; }
  *(u32x4*)(dst)    = a0; *(u32x4*)(dst+8)  = a1;
  *(u32x4*)(dst+16) = a2; *(u32x4*)(dst+24) = a3;
  *(u32x4*)(dst+32) = a4; *(u32x4*)(dst+40) = a5;
}

// ---------------- fp32 -> bf16 convert (strided dst for packing) ---------------
__global__ void k_conv(const float* __restrict__ src, u16* __restrict__ dst,
                       int cols, int sld, int dld){
  const long r = blockIdx.x;
  for (int c = threadIdx.x*4; c < cols; c += 1024) {
    const float* sp = src + r*sld + c;
    float a = sp[0], b = sp[1], cc = sp[2], d = sp[3];
    u64 pack = (u64)f2bf(a) | ((u64)f2bf(b)<<16) | ((u64)f2bf(cc)<<32) | ((u64)f2bf(d)<<48);
    *(u64*)(dst + r*dld + c) = pack;
  }
}

// ---- C(bf16, 4096x3072) = A[b,t0+tt](bf16) @ W(bf16)^T + bias, 128x128 tile ---
__global__ __launch_bounds__(256) void k_gemm(
    const u16* __restrict__ A, const u16* __restrict__ W,
    const float* __restrict__ bias, u16* __restrict__ C, int K, int t0)
{
  __shared__ u16 at[128*40];
  __shared__ u16 bt[128*40];
  const int tid = threadIdx.x;
  const int L = tid & 63, wv = tid >> 6;
  const int mq = wv >> 1, nq = wv & 1;
  const int l16 = L & 15, quad = L >> 4;
  const long mb = blockIdx.y, nb = blockIdx.x;

  f32x4 acc[4][4];
  #pragma unroll
  for (int m=0;m<4;++m)
    #pragma unroll
    for (int n=0;n<4;++n)
      acc[m][n] = (f32x4){0.f,0.f,0.f,0.f};

  const int r = tid >> 1, c0 = (tid & 1) * 16;
  const int fr = (int)mb*128 + r;
  const long arow = ((long)(fr >> 6))*S_ + t0 + (fr & 63);
  const u16* Arow = A + arow*(long)K + c0;
  const u16* Wrow = W + (nb*128 + r)*(long)K + c0;

  for (int kb = 0; kb < K; kb += 32) {
    *(u32x4*)&at[r*40 + c0]     = *(const u32x4*)(Arow + kb);
    *(u32x4*)&at[r*40 + c0 + 8] = *(const u32x4*)(Arow + kb + 8);
    *(u32x4*)&bt[r*40 + c0]     = *(const u32x4*)(Wrow + kb);
    *(u32x4*)&bt[r*40 + c0 + 8] = *(const u32x4*)(Wrow + kb + 8);
    __syncthreads();
    bf16x8 af[4], bfr[4];
    #pragma unroll
    for (int m=0;m<4;++m) af[m]  = *(const bf16x8*)&at[(mq*64 + m*16 + l16)*40 + quad*8];
    #pragma unroll
    for (int n=0;n<4;++n) bfr[n] = *(const bf16x8*)&bt[(nq*64 + n*16 + l16)*40 + quad*8];
    #pragma unroll
    for (int m=0;m<4;++m)
      #pragma unroll
      for (int n=0;n<4;++n)
        acc[m][n] = mfma16(af[m], bfr[n], acc[m][n]);
    __syncthreads();
  }
  #pragma unroll
  for (int n=0;n<4;++n) {
    const long col = nb*128 + nq*64 + n*16 + l16;
    const float bv = bias[col];
    #pragma unroll
    for (int m=0;m<4;++m) {
      const long row0 = mb*128 + mq*64 + m*16 + quad*4;
      #pragma unroll
      for (int rr=0;rr<4;++rr)
        C[(row0+rr)*3072 + col] = f2bf(acc[m][n][rr] + bv);
    }
  }
}

// ------- persistent bilstm segment: 192 wgs = 2 dirs x 2 bhalf x 48 slices -----
// 512 thr = 8 waves = gate q(4) x k-half kh(2); weights persistent in VGPRs.
// Monolithic full-width staging (proven r3 shape) via LLC-direct 16B loads.
// Barrier groups are 48-wide: (dir,mh) recurrences are independent.
// Flags: 256B stride (one per LLC line). Flag store RELAXED (RELEASE's implied
// L2-writeback walk measured ~2ms of the total). Release published before the
// G prefetch so the fence drain doesn't wait on prefetch latency.
__global__ __launch_bounds__(512,2) void k_bilstm(
    const u16* __restrict__ Gf, const u16* __restrict__ Gb,
    const u16* __restrict__ Whhf, const u16* __restrict__ Whhb,
    const u16* __restrict__ h0, u16* __restrict__ lstm,
    float* __restrict__ cstf, float* __restrict__ cstb,
    int* __restrict__ flags, int t0f, int tb0, int ep0)
{
  __shared__ __align__(16) u16 lds[32*776];   // staged 32x768 (+8 pad)
  float* gbuf = (float*)lds;                  // 16KB alias (post-MFMA)
  const int wg = blockIdx.x;
  const int dir = wg / 96, rem = wg % 96, mh = rem / 48, s = rem % 48;
  const int grp = dir*2 + mh;
  const int tid = threadIdx.x;
  const int wave = tid >> 6, q = wave & 3, kh = wave >> 2;
  const int L = tid & 63, l16 = L & 15, quad = L >> 4;
  const int srw = tid >> 4, scl = (tid & 15) * 48;   // 32 rows x 16 chunks

  const u16* Gsrc = dir ? Gb : Gf;
  const u16* W    = dir ? Whhb : Whhf;
  float* cst      = dir ? cstb : cstf;

  bf16x8 bfr[12];
  {
    const u16* wr = W + (long)(q*H_ + s*16 + l16)*H_ + kh*384 + quad*8;
    #pragma unroll
    for (int kk=0;kk<12;++kk) bfr[kk] = *(const bf16x8*)(wr + kk*32);
  }

  const int lb = tid >> 3, cdl = (tid & 7) * 2;
  const int eb = mh*32 + lb, col = s*16 + cdl;
  const bool ew = (tid < 256);
  float creg[2] = {0.f, 0.f};
  if (ew){ creg[0] = cst[eb*H_ + col]; creg[1] = cst[eb*H_ + col + 1]; }

  u32 g0=0,g1=0,g2=0,g3=0;
  if (ew){
    const int tp0 = dir ? (tb0 + SEG-1) : t0f;
    const int gidx = eb*SEG + (dir ? (tp0 - tb0) : (tp0 - t0f));
    const u16* grow = Gsrc + (long)gidx*H4_ + col;
    g0 = *(const u32*)(grow);      g1 = *(const u32*)(grow + H_);
    g2 = *(const u32*)(grow+2*H_); g3 = *(const u32*)(grow+3*H_);
  }

  for (int t=0; t<SEG; ++t) {
    const int tp = dir ? (tb0 + SEG-1 - t) : (t0f + t);
    const bool first = dir ? (tp == S_-1) : (tp == 0);
    const u16* hbase; long ldh;
    if (first){ hbase = h0 + dir*H_; ldh = D2_; }
    else {
      const int tprev = dir ? (tp+1) : (tp-1);
      hbase = lstm + (long)tprev*D2_ + dir*H_;
      ldh = (long)S_*D2_;
    }
    // monolithic stage 32x768 by all 512 threads
    stage48llc(&lds[srw*776 + scl], hbase + (long)(mh*32 + srw)*ldh + scl);
    __syncthreads();
    f32x4 acc[2];
    acc[0] = (f32x4){0.f,0.f,0.f,0.f}; acc[1] = acc[0];
    #pragma unroll
    for (int kk=0;kk<12;++kk)
      #pragma unroll
      for (int m=0;m<2;++m){
        bf16x8 a = *(const bf16x8*)&lds[(m*16+l16)*776 + kh*384 + kk*32 + quad*8];
        acc[m] = mfma16(a, bfr[kk], acc[m]);
      }
    __syncthreads();
    #pragma unroll
    for (int m=0;m<2;++m)
      #pragma unroll
      for (int rr=0;rr<4;++rr)
        gbuf[(q*2+kh)*512 + (m*16+quad*4+rr)*16 + l16] = acc[m][rr];
    __syncthreads();
    if (ew){
      u32 gr[4] = {g0,g1,g2,g3};
      u32 hp = 0;
      #pragma unroll
      for (int i=0;i<2;++i){
        float gv[4];
        #pragma unroll
        for (int qq=0;qq<4;++qq)
          gv[qq] = gbuf[(qq*2+0)*512 + lb*16 + cdl+i]
                 + gbuf[(qq*2+1)*512 + lb*16 + cdl+i]
                 + bf2f((u16)(gr[qq] >> (16*i)));
        const float c = sigm(gv[1])*creg[i] + sigm(gv[0])*tanh_(gv[2]);
        creg[i] = c;
        const float h = sigm(gv[3])*tanh_(c);
        hp |= ((u32)f2bf(h)) << (16*i);
      }
      astore32(lstm + ((long)eb*S_ + tp)*D2_ + dir*H_ + col, hp);
    }
    // ---- release first (fence only drains the h-store), then prefetch, poll ---
    __threadfence_block();
    __syncthreads();
    if (tid == 0)
      __hip_atomic_store(&flags[(grp*48 + s)*64], ep0 + t + 1, __ATOMIC_RELAXED, __HIP_MEMORY_SCOPE_AGENT);
    if (ew){
      // next round's G prefetch overlaps the poll (last-t value unused)
      const int t2 = t + 1;
      const int tp2 = dir ? (tb0 + SEG-1 - t2) : (t0f + t2);
      const long gidx2 = (long)eb*SEG + (dir ? (tp2 - tb0) : (tp2 - t0f));
      const u16* grow2 = Gsrc + gidx2*H4_ + col;
      g0 = *(const u32*)(grow2);      g1 = *(const u32*)(grow2 + H_);
      g2 = *(const u32*)(grow2+2*H_); g3 = *(const u32*)(grow2+3*H_);
    }
    if ((int)tid < 48) {
      while (afload(&flags[(grp*48 + (int)tid)*64]) < ep0 + t + 1)
        __builtin_amdgcn_s_sleep(1);
    }
    __syncthreads();
  }
  if (ew){ cst[eb*H_ + col] = creg[0]; cst[eb*H_ + col + 1] = creg[1]; }
}

// -------- persistent decode: 192 wgs = role(sub/word) x 2 bhalf x 48 slices ----
// role0 computes subword(t=r); role1 computes word(t=r-1). 8-deep U ring
// ([h1|c1|Wh] 64x2304): role0 waits {grp(0,mh)>=r, grp(1,mh)>=r-6 (clobber
// guard — 6 steps of slack takes role1 off role0's critical cycle)};
// role1 waits {grp(0,mh)>=r, grp(1,mh)>=r}. Weights in VGPRs.
// role0 stages its 32x768 h1 MONOLITHICALLY with all 512 threads (one LLC
// round-trip + one barrier fewer on the critical loop than the old 2-phase
// half-stage scheme); all 8 waves then MFMA their kh K-half concurrently.
__global__ __launch_bounds__(512,1) void k_decode(
    const u16* __restrict__ Gsub, const u16* __restrict__ Wsub,
    const u16* __restrict__ Wwrd, const float* __restrict__ wbias,
    const float* __restrict__ clsW, const int* __restrict__ golds,
    u16* __restrict__ U,
    float* __restrict__ scS, float* __restrict__ wcS, float* __restrict__ whS,
    float* __restrict__ partials, int* __restrict__ flags, int r0)
{
  __shared__ __align__(16) u16 ab[2][32*392];   // role1: 2-chunk dbuf; role0: flat 32x776
  float* gbuf = (float*)ab;
  const int wg = blockIdx.x;
  const int role = wg / 96, rem = wg % 96, mh = rem / 48, s = rem % 48;
  const int grp = role*2 + mh;
  const int tid = threadIdx.x;
  const int wave = tid >> 6, q = wave & 3, kh = wave >> 2;
  const int L = tid & 63, l16 = L & 15, quad = L >> 4;
  const int su = tid & 255, srw = su >> 3, scl = (su & 7) * 48;   // role1 map (256 thr)
  const int srw0 = tid >> 4, scl0 = (tid & 15) * 48;              // role0 map (512 thr)
  const int lb = tid >> 3, cdl = (tid & 7)*2;
  const int eb = mh*32 + lb, col = s*16 + cdl;
  const bool ew = (tid < 256);
  const int sb  = mh*32 + srw;    // role1 staged row (batch)
  const int sb0 = mh*32 + srw0;   // role0 staged row (batch)
  u16* abf = &ab[0][0];           // role0 flat buffer, stride 776

  bf16x8 wfr[36];
  float st0[2] = {0.f,0.f}, st1[2] = {0.f,0.f}, st2[2] = {0.f,0.f};
  float wbv[4][2], clv[2][2];
  if (role == 0){
    const u16* wr = Wsub + (long)(q*H_ + s*16 + l16)*H_ + kh*384 + quad*8;
    #pragma unroll
    for (int kk=0;kk<12;++kk) wfr[kk] = *(const bf16x8*)(wr + kk*32);
    if (ew){ st0[0] = scS[eb*H_+col]; st0[1] = scS[eb*H_+col+1]; }
  } else {
    const u16* wr = Wwrd + (long)(q*H_ + s*16 + l16)*2304 + kh*384 + quad*8;
    #pragma unroll
    for (int cc=0;cc<3;++cc)
      #pragma unroll
      for (int kk=0;kk<12;++kk)
        wfr[cc*12+kk] = *(const bf16x8*)(wr + cc*768 + kk*32);
    if (ew){
      st1[0] = wcS[eb*H_+col]; st1[1] = wcS[eb*H_+col+1];
      st2[0] = whS[eb*H_+col]; st2[1] = whS[eb*H_+col+1];
      #pragma unroll
      for (int qq=0;qq<4;++qq){ wbv[qq][0]=wbias[qq*H_+col]; wbv[qq][1]=wbias[qq*H_+col+1]; }
      clv[0][0]=clsW[col]; clv[0][1]=clsW[col+1];
      clv[1][0]=clsW[2304+col]; clv[1][1]=clsW[2304+col+1];
    }
  }

  int stg_g = golds[sb0*S_ + ((r0 < 255) ? r0 : 255)];   // staging mask carry (role0)

  for (int rr=0; rr<SEG; ++rr){
    const int r = r0 + rr;
    // ---- flag-independent loads issued BEFORE the wait (latency hides) ----
    u32 g0=0,g1=0,g2=0,g3=0; int gld_e = 0, gld = 0;
    if (ew){
      if (role == 0 && r <= 254){
        gld_e = golds[eb*S_ + r + 1];
        const u16* grow = Gsub + ((long)eb*SEG + rr)*H4_ + col;
        g0 = *(const u32*)(grow);      g1 = *(const u32*)(grow + H_);
        g2 = *(const u32*)(grow+2*H_); g3 = *(const u32*)(grow+3*H_);
      } else if (role == 1 && r >= 1){
        gld = golds[eb*S_ + r];
      }
    }
    // ---- decoupled 48-wide waits (256B-strided flags) ----
    if (tid < 96){
      int idx, tgt;
      if (tid < 48){ idx = mh*48 + tid; tgt = r; }
      else { idx = (2+mh)*48 + (tid-48); tgt = (role==0) ? (r-6) : r; }
      while (afload(&flags[idx*64]) < tgt) __builtin_amdgcn_s_sleep(1);
    }
    __syncthreads();

    const u16* Uprev = U + ((r+7)&7)*(long)USZ;
    u16*       Ucur  = U + (r&7)*(long)USZ;

    if (role == 0){
      if (r <= 254){
        const bool keep_s = (r > 0) && (stg_g == 0);
        // monolithic 512-thread stage of the full 32x768 h1 block
        stage48llcz(&abf[srw0*776 + scl0], Uprev + (long)sb0*2304 + scl0, keep_s);
        __syncthreads();
        f32x4 acc[2];
        acc[0] = (f32x4){0.f,0.f,0.f,0.f}; acc[1] = acc[0];
        #pragma unroll
        for (int kk=0;kk<12;++kk)
          #pragma unroll
          for (int m=0;m<2;++m){
            bf16x8 a = *(const bf16x8*)&abf[(m*16+l16)*776 + kh*384 + kk*32 + quad*8];
            acc[m] = mfma16(a, wfr[kk], acc[m]);
          }
        __syncthreads();
        stg_g = golds[sb0*S_ + ((r+1 < 255) ? r+1 : 255)];
        #pragma unroll
        for (int m=0;m<2;++m)
          #pragma unroll
          for (int r4=0;r4<4;++r4)
            gbuf[(q*2+kh)*512 + (m*16+quad*4+r4)*16 + l16] = acc[m][r4];
        __syncthreads();
        if (ew){
          const bool keep = (gld_e == 0);
          u32 gr[4] = {g0,g1,g2,g3};
          u32 hp=0, cp=0;
          #pragma unroll
          for (int i=0;i<2;++i){
            float gv[4];
            #pragma unroll
            for (int qq=0;qq<4;++qq)
              gv[qq] = gbuf[(qq*2+0)*512 + lb*16 + cdl+i]
                     + gbuf[(qq*2+1)*512 + lb*16 + cdl+i]
                     + bf2f((u16)(gr[qq] >> (16*i)));
            const float c1 = sigm(gv[1])*st0[i] + sigm(gv[0])*tanh_(gv[2]);
            const float h1 = sigm(gv[3])*tanh_(c1);
            st0[i] = keep ? c1 : 0.f;
            hp |= ((u32)f2bf(h1)) << (16*i);
            cp |= ((u32)f2bf(c1)) << (16*i);
          }
          astore32(Ucur + (long)eb*2304 + col, hp);
          astore32(Ucur + (long)eb*2304 + H_ + col, cp);
        }
      }
    } else {
      if (r >= 1){
        const u16* urow = Uprev + (long)sb*2304;
        if (kh == 0){                        // pre-stage chunk0
          stage48llc(&ab[0][srw*392 + scl], urow + scl);
        }
        __syncthreads();
        f32x4 acc[2];
        acc[0] = (f32x4){0.f,0.f,0.f,0.f}; acc[1] = acc[0];
        #pragma unroll
        for (int p=0;p<6;++p){
          if ((p & 1) == kh){                // consume chunk p
            const int cc = p >> 1;
            #pragma unroll
            for (int kk=0;kk<12;++kk)
              #pragma unroll
              for (int m=0;m<2;++m){
                bf16x8 a = *(const bf16x8*)&ab[p&1][(m*16+l16)*392 + kk*32 + quad*8];
                acc[m] = mfma16(a, wfr[cc*12+kk], acc[m]);
              }
          } else if (p < 5){                 // stage chunk p+1
            stage48llc(&ab[(p+1)&1][srw*392 + scl], urow + (p+1)*384 + scl);
          }
          __syncthreads();
        }
        #pragma unroll
        for (int m=0;m<2;++m)
          #pragma unroll
          for (int r4=0;r4<4;++r4)
            gbuf[(q*2+kh)*512 + (m*16+quad*4+r4)*16 + l16] = acc[m][r4];
        __syncthreads();
        if (ew){
          const bool keep = (gld == 0);
          const int tp = r - 1;
          float p0 = 0.f, p1 = 0.f;
          u32 wp = 0;
          #pragma unroll
          for (int i=0;i<2;++i){
            float gv[4];
            #pragma unroll
            for (int qq=0;qq<4;++qq)
              gv[qq] = gbuf[(qq*2+0)*512 + lb*16 + cdl+i]
                     + gbuf[(qq*2+1)*512 + lb*16 + cdl+i]
                     + wbv[qq][i];
            const float wc1 = sigm(gv[1])*st1[i] + sigm(gv[0])*tanh_(gv[2]);
            const float wh1 = sigm(gv[3])*tanh_(wc1);
            st1[i] = keep ? st1[i] : wc1;
            st2[i] = keep ? st2[i] : wh1;
            p0 += wh1 * clv[0][i];
            p1 += wh1 * clv[1][i];
            wp |= ((u32)f2bf(st2[i])) << (16*i);
          }
          astore32(Ucur + (long)eb*2304 + D2_ + col, wp);
          p0 += __shfl_xor(p0, 1); p0 += __shfl_xor(p0, 2); p0 += __shfl_xor(p0, 4);
          p1 += __shfl_xor(p1, 1); p1 += __shfl_xor(p1, 2); p1 += __shfl_xor(p1, 4);
          if ((tid & 7) == 0){
            float* pp = partials + ((long)(tp*48 + s)*64 + eb)*2;
            pp[0] = p0; pp[1] = p1;
          }
        }
      }
    }
    // ---- release own flag (256B stride, relaxed) ----
    __threadfence_block();
    __syncthreads();
    if (tid == 0)
      __hip_atomic_store(&flags[(grp*48 + s)*64], r+1, __ATOMIC_RELAXED, __HIP_MEMORY_SCOPE_AGENT);
  }
  if (ew){
    if (role == 0){
      scS[eb*H_+col] = st0[0]; scS[eb*H_+col+1] = st0[1];
    } else {
      wcS[eb*H_+col] = st1[0]; wcS[eb*H_+col+1] = st1[1];
      whS[eb*H_+col] = st2[0]; whS[eb*H_+col+1] = st2[1];
    }
  }
}

// ---------------- classifier epilogue: out = first | cls_b + wh-part + x-part --
__global__ __launch_bounds__(256) void k_cls(
    const u16* __restrict__ lstm, const float* __restrict__ partials,
    const float* __restrict__ clsW, const float* __restrict__ clsb,
    float* __restrict__ out)
{
  const int ts = blockIdx.x;
  const int b  = blockIdx.y;
  const int tid = threadIdx.x;
  if (ts == 0) {
    if (tid == 0) { out[(long)b*S_*2 + 0] = -1.f; out[(long)b*S_*2 + 1] = 1.f; }
    return;
  }
  const int t = ts - 1;
  float s0 = 0.f, s1 = 0.f;
  const u16* xr = lstm + ((long)b*S_ + ts)*D2_;
  for (int k = tid; k < D2_; k += 256) {
    const float xv = bf2f(xr[k]);
    s0 += xv * clsW[768 + k];
    s1 += xv * clsW[2304 + 768 + k];
  }
  if (tid < 48) {
    const float* pr = partials + ((long)(t*48 + tid)*64 + b)*2;
    s0 += pr[0]; s1 += pr[1];
  }
  __shared__ float r0[256], r1[256];
  r0[tid] = s0; r1[tid] = s1; __syncthreads();
  for (int off = 128; off > 0; off >>= 1) {
    if (tid < off) { r0[tid] += r0[tid+off]; r1[tid] += r1[tid+off]; }
    __syncthreads();
  }
  if (tid == 0) {
    out[((long)b*S_ + ts)*2 + 0] = r0[0] + clsb[0];
    out[((long)b*S_ + ts)*2 + 1] = r1[0] + clsb[1];
  }
}

extern "C" void kernel_launch(void* const* d_in, const int* in_sizes, int n_in,
                              void* d_out, int out_size, void* d_ws, size_t ws_size,
                              hipStream_t stream)
{
  (void)in_sizes; (void)n_in; (void)out_size; (void)ws_size;
  const float* x     = (const float*)d_in[0];
  const int*   golds = (const int*)d_in[1];
  const float* wihf  = (const float*)d_in[2];
  const float* whhf  = (const float*)d_in[3];
  const float* bfw   = (const float*)d_in[4];
  const float* wihb  = (const float*)d_in[5];
  const float* whhb  = (const float*)d_in[6];
  const float* bbw   = (const float*)d_in[7];
  const float* swih  = (const float*)d_in[8];
  const float* swhh  = (const float*)d_in[9];
  const float* sb    = (const float*)d_in[10];
  const float* wwih  = (const float*)d_in[11];
  const float* wwhh  = (const float*)d_in[12];
  const float* wb    = (const float*)d_in[13];
  const float* clsW  = (const float*)d_in[14];
  const float* clsb  = (const float*)d_in[15];
  float* out = (float*)d_out;

  char* base = (char*)d_ws;
  // -------- zero-init region (memset each launch) ------------------------------
  u16*   h0   = (u16*)(base + 0);            // zeros during bilstm (1.18MB region)
  int*   flg2 = (int*)(base + 1179648);      // bilstm flags: 192 slots * 256 B
  int*   flg4 = (int*)(base + 1228800);      // decode flags
  float* cstf = (float*)(base + 1277952);    // bilstm fwd c-state 64x768 f32
  float* cstb = (float*)(base + 1474560);
  float* scS  = (float*)(base + 1671168);    // decode subword c
  float* wcS  = (float*)(base + 1867776);    // decode word c
  float* whS  = (float*)(base + 2064384);    // decode word h
  // zero region ends at 2,260,992
  // -------- scratch (fully written before read) --------------------------------
  u16* xb     = (u16*)(base + 2260992);
  u16* wihf_b = (u16*)(base + 27426816);
  u16* whhf_b = (u16*)(base + 32145408);
  u16* wihb_b = (u16*)(base + 36864000);
  u16* whhb_b = (u16*)(base + 41582592);
  u16* swih_b = (u16*)(base + 46301184);     // 3072x1536
  u16* swhh_b = (u16*)(base + 55738368);     // 3072x768
  u16* wwrd_b = (u16*)(base + 60456960);     // packed [word_Wih | word_Whh] 3072x2304
  u16* Gfseg  = (u16*)(base + 74612736);     // 4096x3072 bf16 segment
  u16* Gbseg  = (u16*)(base + 99778560);
  u16* lstm   = (u16*)(base + 124944384);    // (B,S,1536) bf16
  // total footprint: 175,276,032 B (unchanged)
  u16* Gsubseg = Gfseg;
  float* prt   = (float*)Gbseg;              // partials: 6.27MB at Gbseg+0 (decode)
  // 8-deep U ring (2.36MB) lives in dead Gbseg scratch after partials;
  // zeroed by a second memset between the bilstm and decode phases.
  u16* U       = (u16*)(base + 99778560 + 8388608);   // Gbseg + 8MB

  hipMemsetAsync(d_ws, 0, 2260992, stream);

  k_conv<<<16384, 256, 0, stream>>>(x,    xb,     768,  768,  768);
  k_conv<<<3072,  256, 0, stream>>>(wihf, wihf_b, 768,  768,  768);
  k_conv<<<3072,  256, 0, stream>>>(whhf, whhf_b, 768,  768,  768);
  k_conv<<<3072,  256, 0, stream>>>(wihb, wihb_b, 768,  768,  768);
  k_conv<<<3072,  256, 0, stream>>>(whhb, whhb_b, 768,  768,  768);
  k_conv<<<3072,  256, 0, stream>>>(swih, swih_b, 1536, 1536, 1536);
  k_conv<<<3072,  256, 0, stream>>>(swhh, swhh_b, 768,  768,  768);
  k_conv<<<3072,  256, 0, stream>>>(wwih, wwrd_b,        1536, 1536, 2304);
  k_conv<<<3072,  256, 0, stream>>>(wwhh, wwrd_b + 1536, 768,  768,  2304);

  dim3 gg(24, 32);
  for (int sgi = 0; sgi < 4; ++sgi) {
    const int t0f = sgi*SEG;
    const int tb0 = (3 - sgi)*SEG;
    k_gemm<<<gg, 256, 0, stream>>>(xb, wihf_b, bfw, Gfseg, 768, t0f);
    k_gemm<<<gg, 256, 0, stream>>>(xb, wihb_b, bbw, Gbseg, 768, tb0);
    k_bilstm<<<192, 512, 0, stream>>>(Gfseg, Gbseg, whhf_b, whhb_b, h0, lstm,
                                      cstf, cstb, flg2, t0f, tb0, sgi*SEG);
  }

  // zero the 8-deep U ring (Gbseg scratch was clobbered by bilstm-phase gemms)
  hipMemsetAsync(U, 0, 8*USZ*2, stream);

  for (int sgi = 0; sgi < 4; ++sgi) {
    const int r0 = sgi*SEG;
    k_gemm<<<gg, 256, 0, stream>>>(lstm, swih_b, sb, Gsubseg, 1536, r0);
    k_decode<<<192, 512, 0, stream>>>(Gsubseg, swhh_b, wwrd_b, wb, clsW, golds,
                                      U, scS, wcS, whS, prt, flg4, r0);
  }

  dim3 gc(256, 64);
  k_cls<<<gc, 256, 0, stream>>>(lstm, prt, clsW, clsb, out);
}

// Round 7
// 4131.026 us; speedup vs baseline: 1.0067x; 1.0067x over previous
//
#include <hip/hip_runtime.h>

#define B_  64
#define S_  256
#define H_  768
#define H4_ 3072
#define D2_ 1536
#define SEG 64
#define USZ (64*2304)

using u16 = unsigned short;
using u32 = unsigned int;
using u64 = unsigned long long;
typedef __attribute__((ext_vector_type(8))) short bf16x8;
typedef __attribute__((ext_vector_type(4))) float f32x4;
typedef __attribute__((ext_vector_type(4))) unsigned int u32x4;

#define DEV __device__ __forceinline__

DEV float bf2f(u16 u){ union{u32 i; float f;} c; c.i = ((u32)u)<<16; return c.f; }
DEV u16 f2bf(float f){ union{float f; u32 i;} c; c.f = f; return (u16)((c.i + 0x7FFFu + ((c.i>>16)&1u)) >> 16); }
DEV float sigm(float x){ return 1.f/(1.f + __expf(-x)); }
DEV float tanh_(float x){ return 2.f/(1.f + __expf(-2.f*x)) - 1.f; }

// agent-scope publication / flag ops
DEV void astore32(u16* p, u32 v){ __hip_atomic_store((u32*)p, v, __ATOMIC_RELAXED, __HIP_MEMORY_SCOPE_AGENT); }
DEV int afload(const int* p){ return __hip_atomic_load(p, __ATOMIC_RELAXED, __HIP_MEMORY_SCOPE_AGENT); }

DEV f32x4 mfma16(bf16x8 a, bf16x8 b, f32x4 c){
  return __builtin_amdgcn_mfma_f32_16x16x32_bf16(a, b, c, 0, 0, 0);
}

// 96B (48 u16) coherent staging load: 6 x dwordx4 bypassing L1/L2 (sc0 sc1 ->
// LLC-direct), one vmcnt drain.
DEV void llc_load96(const u16* p, u32x4& a0, u32x4& a1, u32x4& a2,
                    u32x4& a3, u32x4& a4, u32x4& a5){
  asm volatile(
    "global_load_dwordx4 %0, %6, off sc0 sc1\n\t"
    "global_load_dwordx4 %1, %6, off offset:16 sc0 sc1\n\t"
    "global_load_dwordx4 %2, %6, off offset:32 sc0 sc1\n\t"
    "global_load_dwordx4 %3, %6, off offset:48 sc0 sc1\n\t"
    "global_load_dwordx4 %4, %6, off offset:64 sc0 sc1\n\t"
    "global_load_dwordx4 %5, %6, off offset:80 sc0 sc1\n\t"
    "s_waitcnt vmcnt(0)"
    : "=&v"(a0), "=&v"(a1), "=&v"(a2), "=&v"(a3), "=&v"(a4), "=&v"(a5)
    : "v"(p));
}
// non-waiting variant: issue only; caller must vmwait0() before consuming.
DEV void llc_load96_nw(const u16* p, u32x4& a0, u32x4& a1, u32x4& a2,
                       u32x4& a3, u32x4& a4, u32x4& a5){
  asm volatile(
    "global_load_dwordx4 %0, %6, off sc0 sc1\n\t"
    "global_load_dwordx4 %1, %6, off offset:16 sc0 sc1\n\t"
    "global_load_dwordx4 %2, %6, off offset:32 sc0 sc1\n\t"
    "global_load_dwordx4 %3, %6, off offset:48 sc0 sc1\n\t"
    "global_load_dwordx4 %4, %6, off offset:64 sc0 sc1\n\t"
    "global_load_dwordx4 %5, %6, off offset:80 sc0 sc1"
    : "=&v"(a0), "=&v"(a1), "=&v"(a2), "=&v"(a3), "=&v"(a4), "=&v"(a5)
    : "v"(p));
}
DEV void vmwait0(){ asm volatile("s_waitcnt vmcnt(0)" ::: "memory"); }

DEV void stage48llc(u16* dst, const u16* src){
  u32x4 a0,a1,a2,a3,a4,a5;
  llc_load96(src, a0,a1,a2,a3,a4,a5);
  *(u32x4*)(dst)    = a0; *(u32x4*)(dst+8)  = a1;
  *(u32x4*)(dst+16) = a2; *(u32x4*)(dst+24) = a3;
  *(u32x4*)(dst+32) = a4; *(u32x4*)(dst+40) = a5;
}
DEV void stage48llcz(u16* dst, const u16* src, bool keep){
  u32x4 a0,a1,a2,a3,a4,a5;
  llc_load96(src, a0,a1,a2,a3,a4,a5);
  const u32x4 z = {0u,0u,0u,0u};
  if (!keep){ a0=z; a1=z; a2=z; a3=z; a4=z; a5=z; }
  *(u32x4*)(dst)    = a0; *(u32x4*)(dst+8)  = a1;
  *(u32x4*)(dst+16) = a2; *(u32x4*)(dst+24) = a3;
  *(u32x4*)(dst+32) = a4; *(u32x4*)(dst+40) = a5;
}
DEV void wr48(u16* dst, const u32x4* a){
  *(u32x4*)(dst)    = a[0]; *(u32x4*)(dst+8)  = a[1];
  *(u32x4*)(dst+16) = a[2]; *(u32x4*)(dst+24) = a[3];
  *(u32x4*)(dst+32) = a[4]; *(u32x4*)(dst+40) = a[5];
}

// ---------------- fp32 -> bf16 convert (strided dst for packing) ---------------
__global__ void k_conv(const float* __restrict__ src, u16* __restrict__ dst,
                       int cols, int sld, int dld){
  const long r = blockIdx.x;
  for (int c = threadIdx.x*4; c < cols; c += 1024) {
    const float* sp = src + r*sld + c;
    float a = sp[0], b = sp[1], cc = sp[2], d = sp[3];
    u64 pack = (u64)f2bf(a) | ((u64)f2bf(b)<<16) | ((u64)f2bf(cc)<<32) | ((u64)f2bf(d)<<48);
    *(u64*)(dst + r*dld + c) = pack;
  }
}

// ---- C(bf16, 4096x3072) = A[b,t0+tt](bf16) @ W(bf16)^T + bias, 128x128 tile ---
__global__ __launch_bounds__(256) void k_gemm(
    const u16* __restrict__ A, const u16* __restrict__ W,
    const float* __restrict__ bias, u16* __restrict__ C, int K, int t0)
{
  __shared__ u16 at[128*40];
  __shared__ u16 bt[128*40];
  const int tid = threadIdx.x;
  const int L = tid & 63, wv = tid >> 6;
  const int mq = wv >> 1, nq = wv & 1;
  const int l16 = L & 15, quad = L >> 4;
  const long mb = blockIdx.y, nb = blockIdx.x;

  f32x4 acc[4][4];
  #pragma unroll
  for (int m=0;m<4;++m)
    #pragma unroll
    for (int n=0;n<4;++n)
      acc[m][n] = (f32x4){0.f,0.f,0.f,0.f};

  const int r = tid >> 1, c0 = (tid & 1) * 16;
  const int fr = (int)mb*128 + r;
  const long arow = ((long)(fr >> 6))*S_ + t0 + (fr & 63);
  const u16* Arow = A + arow*(long)K + c0;
  const u16* Wrow = W + (nb*128 + r)*(long)K + c0;

  for (int kb = 0; kb < K; kb += 32) {
    *(u32x4*)&at[r*40 + c0]     = *(const u32x4*)(Arow + kb);
    *(u32x4*)&at[r*40 + c0 + 8] = *(const u32x4*)(Arow + kb + 8);
    *(u32x4*)&bt[r*40 + c0]     = *(const u32x4*)(Wrow + kb);
    *(u32x4*)&bt[r*40 + c0 + 8] = *(const u32x4*)(Wrow + kb + 8);
    __syncthreads();
    bf16x8 af[4], bfr[4];
    #pragma unroll
    for (int m=0;m<4;++m) af[m]  = *(const bf16x8*)&at[(mq*64 + m*16 + l16)*40 + quad*8];
    #pragma unroll
    for (int n=0;n<4;++n) bfr[n] = *(const bf16x8*)&bt[(nq*64 + n*16 + l16)*40 + quad*8];
    #pragma unroll
    for (int m=0;m<4;++m)
      #pragma unroll
      for (int n=0;n<4;++n)
        acc[m][n] = mfma16(af[m], bfr[n], acc[m][n]);
    __syncthreads();
  }
  #pragma unroll
  for (int n=0;n<4;++n) {
    const long col = nb*128 + nq*64 + n*16 + l16;
    const float bv = bias[col];
    #pragma unroll
    for (int m=0;m<4;++m) {
      const long row0 = mb*128 + mq*64 + m*16 + quad*4;
      #pragma unroll
      for (int rr=0;rr<4;++rr)
        C[(row0+rr)*3072 + col] = f2bf(acc[m][n][rr] + bv);
    }
  }
}

// ------- persistent bilstm segment: 192 wgs = 2 dirs x 2 bhalf x 48 slices -----
// 512 thr = 8 waves = gate q(4) x k-half kh(2); weights persistent in VGPRs.
// Monolithic full-width staging via LLC-direct 16B loads. Flags 256B stride,
// RELAXED store (RELEASE's implied L2 writeback walk cost ~2ms total).
__global__ __launch_bounds__(512,2) void k_bilstm(
    const u16* __restrict__ Gf, const u16* __restrict__ Gb,
    const u16* __restrict__ Whhf, const u16* __restrict__ Whhb,
    const u16* __restrict__ h0, u16* __restrict__ lstm,
    float* __restrict__ cstf, float* __restrict__ cstb,
    int* __restrict__ flags, int t0f, int tb0, int ep0)
{
  __shared__ __align__(16) u16 lds[32*776];   // staged 32x768 (+8 pad)
  float* gbuf = (float*)lds;                  // 16KB alias (post-MFMA)
  const int wg = blockIdx.x;
  const int dir = wg / 96, rem = wg % 96, mh = rem / 48, s = rem % 48;
  const int grp = dir*2 + mh;
  const int tid = threadIdx.x;
  const int wave = tid >> 6, q = wave & 3, kh = wave >> 2;
  const int L = tid & 63, l16 = L & 15, quad = L >> 4;
  const int srw = tid >> 4, scl = (tid & 15) * 48;   // 32 rows x 16 chunks

  const u16* Gsrc = dir ? Gb : Gf;
  const u16* W    = dir ? Whhb : Whhf;
  float* cst      = dir ? cstb : cstf;

  bf16x8 bfr[12];
  {
    const u16* wr = W + (long)(q*H_ + s*16 + l16)*H_ + kh*384 + quad*8;
    #pragma unroll
    for (int kk=0;kk<12;++kk) bfr[kk] = *(const bf16x8*)(wr + kk*32);
  }

  const int lb = tid >> 3, cdl = (tid & 7) * 2;
  const int eb = mh*32 + lb, col = s*16 + cdl;
  const bool ew = (tid < 256);
  float creg[2] = {0.f, 0.f};
  if (ew){ creg[0] = cst[eb*H_ + col]; creg[1] = cst[eb*H_ + col + 1]; }

  u32 g0=0,g1=0,g2=0,g3=0;
  if (ew){
    const int tp0 = dir ? (tb0 + SEG-1) : t0f;
    const int gidx = eb*SEG + (dir ? (tp0 - tb0) : (tp0 - t0f));
    const u16* grow = Gsrc + (long)gidx*H4_ + col;
    g0 = *(const u32*)(grow);      g1 = *(const u32*)(grow + H_);
    g2 = *(const u32*)(grow+2*H_); g3 = *(const u32*)(grow+3*H_);
  }

  for (int t=0; t<SEG; ++t) {
    const int tp = dir ? (tb0 + SEG-1 - t) : (t0f + t);
    const bool first = dir ? (tp == S_-1) : (tp == 0);
    const u16* hbase; long ldh;
    if (first){ hbase = h0 + dir*H_; ldh = D2_; }
    else {
      const int tprev = dir ? (tp+1) : (tp-1);
      hbase = lstm + (long)tprev*D2_ + dir*H_;
      ldh = (long)S_*D2_;
    }
    // monolithic stage 32x768 by all 512 threads
    stage48llc(&lds[srw*776 + scl], hbase + (long)(mh*32 + srw)*ldh + scl);
    __syncthreads();
    f32x4 acc[2];
    acc[0] = (f32x4){0.f,0.f,0.f,0.f}; acc[1] = acc[0];
    #pragma unroll
    for (int kk=0;kk<12;++kk)
      #pragma unroll
      for (int m=0;m<2;++m){
        bf16x8 a = *(const bf16x8*)&lds[(m*16+l16)*776 + kh*384 + kk*32 + quad*8];
        acc[m] = mfma16(a, bfr[kk], acc[m]);
      }
    __syncthreads();
    #pragma unroll
    for (int m=0;m<2;++m)
      #pragma unroll
      for (int rr=0;rr<4;++rr)
        gbuf[(q*2+kh)*512 + (m*16+quad*4+rr)*16 + l16] = acc[m][rr];
    __syncthreads();
    if (ew){
      u32 gr[4] = {g0,g1,g2,g3};
      u32 hp = 0;
      #pragma unroll
      for (int i=0;i<2;++i){
        float gv[4];
        #pragma unroll
        for (int qq=0;qq<4;++qq)
          gv[qq] = gbuf[(qq*2+0)*512 + lb*16 + cdl+i]
                 + gbuf[(qq*2+1)*512 + lb*16 + cdl+i]
                 + bf2f((u16)(gr[qq] >> (16*i)));
        const float c = sigm(gv[1])*creg[i] + sigm(gv[0])*tanh_(gv[2]);
        creg[i] = c;
        const float h = sigm(gv[3])*tanh_(c);
        hp |= ((u32)f2bf(h)) << (16*i);
      }
      astore32(lstm + ((long)eb*S_ + tp)*D2_ + dir*H_ + col, hp);
    }
    // ---- release first (fence only drains the h-store), then prefetch, poll ---
    __threadfence_block();
    __syncthreads();
    if (tid == 0)
      __hip_atomic_store(&flags[(grp*48 + s)*64], ep0 + t + 1, __ATOMIC_RELAXED, __HIP_MEMORY_SCOPE_AGENT);
    if (ew){
      // next round's G prefetch overlaps the poll (last-t value unused)
      const int t2 = t + 1;
      const int tp2 = dir ? (tb0 + SEG-1 - t2) : (t0f + t2);
      const long gidx2 = (long)eb*SEG + (dir ? (tp2 - tb0) : (tp2 - t0f));
      const u16* grow2 = Gsrc + gidx2*H4_ + col;
      g0 = *(const u32*)(grow2);      g1 = *(const u32*)(grow2 + H_);
      g2 = *(const u32*)(grow2+2*H_); g3 = *(const u32*)(grow2+3*H_);
    }
    if ((int)tid < 48) {
      while (afload(&flags[(grp*48 + (int)tid)*64]) < ep0 + t + 1)
        __builtin_amdgcn_s_sleep(1);
    }
    __syncthreads();
  }
  if (ew){ cst[eb*H_ + col] = creg[0]; cst[eb*H_ + col + 1] = creg[1]; }
}

// -------- persistent decode: 192 wgs = role(sub/word) x 2 bhalf x 48 slices ----
// role0 computes subword(t=r); role1 computes word(t=r-1). 8-deep U ring;
// role0 guard r-6 (role1 off role0's cycle); role1 waits role0>=r, role1>=r.
// role0: monolithic 512-thread stage of 32x768 h1, then all 8 waves MFMA.
// role1: MLP register staging — issue chunks 0+1 (12 dwordx4 in flight), one
// vmcnt, LDS-write both; issue chunk2 so its RT overlaps the chunk0/1 MFMAs.
// Collapses role1's 6 serial LLC round-trips (the measured binder) to ~1.5.
__global__ __launch_bounds__(512,1) void k_decode(
    const u16* __restrict__ Gsub, const u16* __restrict__ Wsub,
    const u16* __restrict__ Wwrd, const float* __restrict__ wbias,
    const float* __restrict__ clsW, const int* __restrict__ golds,
    u16* __restrict__ U,
    float* __restrict__ scS, float* __restrict__ wcS, float* __restrict__ whS,
    float* __restrict__ partials, int* __restrict__ flags, int r0)
{
  __shared__ __align__(16) u16 ab[3][32*776];   // role1: 3 chunk buffers; role0: ab[0]
  float* gbuf = (float*)ab;
  const int wg = blockIdx.x;
  const int role = wg / 96, rem = wg % 96, mh = rem / 48, s = rem % 48;
  const int grp = role*2 + mh;
  const int tid = threadIdx.x;
  const int wave = tid >> 6, q = wave & 3, kh = wave >> 2;
  const int L = tid & 63, l16 = L & 15, quad = L >> 4;
  const int srw0 = tid >> 4, scl0 = (tid & 15) * 48;   // 512-thread stage map
  const int lb = tid >> 3, cdl = (tid & 7)*2;
  const int eb = mh*32 + lb, col = s*16 + cdl;
  const bool ew = (tid < 256);
  const int sb0 = mh*32 + srw0;   // staged row (batch)
  u16* abf = &ab[0][0];           // role0 flat buffer, stride 776

  bf16x8 wfr[36];
  float st0[2] = {0.f,0.f}, st1[2] = {0.f,0.f}, st2[2] = {0.f,0.f};
  float wbv[4][2], clv[2][2];
  if (role == 0){
    const u16* wr = Wsub + (long)(q*H_ + s*16 + l16)*H_ + kh*384 + quad*8;
    #pragma unroll
    for (int kk=0;kk<12;++kk) wfr[kk] = *(const bf16x8*)(wr + kk*32);
    if (ew){ st0[0] = scS[eb*H_+col]; st0[1] = scS[eb*H_+col+1]; }
  } else {
    const u16* wr = Wwrd + (long)(q*H_ + s*16 + l16)*2304 + kh*384 + quad*8;
    #pragma unroll
    for (int cc=0;cc<3;++cc)
      #pragma unroll
      for (int kk=0;kk<12;++kk)
        wfr[cc*12+kk] = *(const bf16x8*)(wr + cc*768 + kk*32);
    if (ew){
      st1[0] = wcS[eb*H_+col]; st1[1] = wcS[eb*H_+col+1];
      st2[0] = whS[eb*H_+col]; st2[1] = whS[eb*H_+col+1];
      #pragma unroll
      for (int qq=0;qq<4;++qq){ wbv[qq][0]=wbias[qq*H_+col]; wbv[qq][1]=wbias[qq*H_+col+1]; }
      clv[0][0]=clsW[col]; clv[0][1]=clsW[col+1];
      clv[1][0]=clsW[2304+col]; clv[1][1]=clsW[2304+col+1];
    }
  }

  int stg_g = golds[sb0*S_ + ((r0 < 255) ? r0 : 255)];   // staging mask carry (role0)

  for (int rr=0; rr<SEG; ++rr){
    const int r = r0 + rr;
    // ---- flag-independent loads issued BEFORE the wait (latency hides) ----
    u32 g0=0,g1=0,g2=0,g3=0; int gld_e = 0, gld = 0;
    if (ew){
      if (role == 0 && r <= 254){
        gld_e = golds[eb*S_ + r + 1];
        const u16* grow = Gsub + ((long)eb*SEG + rr)*H4_ + col;
        g0 = *(const u32*)(grow);      g1 = *(const u32*)(grow + H_);
        g2 = *(const u32*)(grow+2*H_); g3 = *(const u32*)(grow+3*H_);
      } else if (role == 1 && r >= 1){
        gld = golds[eb*S_ + r];
      }
    }
    // ---- decoupled 48-wide waits (256B-strided flags) ----
    if (tid < 96){
      int idx, tgt;
      if (tid < 48){ idx = mh*48 + tid; tgt = r; }
      else { idx = (2+mh)*48 + (tid-48); tgt = (role==0) ? (r-6) : r; }
      while (afload(&flags[idx*64]) < tgt) __builtin_amdgcn_s_sleep(1);
    }
    __syncthreads();

    const u16* Uprev = U + ((r+7)&7)*(long)USZ;
    u16*       Ucur  = U + (r&7)*(long)USZ;

    if (role == 0){
      if (r <= 254){
        const bool keep_s = (r > 0) && (stg_g == 0);
        // monolithic 512-thread stage of the full 32x768 h1 block
        stage48llcz(&abf[srw0*776 + scl0], Uprev + (long)sb0*2304 + scl0, keep_s);
        __syncthreads();
        f32x4 acc[2];
        acc[0] = (f32x4){0.f,0.f,0.f,0.f}; acc[1] = acc[0];
        #pragma unroll
        for (int kk=0;kk<12;++kk)
          #pragma unroll
          for (int m=0;m<2;++m){
            bf16x8 a = *(const bf16x8*)&abf[(m*16+l16)*776 + kh*384 + kk*32 + quad*8];
            acc[m] = mfma16(a, wfr[kk], acc[m]);
          }
        __syncthreads();
        stg_g = golds[sb0*S_ + ((r+1 < 255) ? r+1 : 255)];
        #pragma unroll
        for (int m=0;m<2;++m)
          #pragma unroll
          for (int r4=0;r4<4;++r4)
            gbuf[(q*2+kh)*512 + (m*16+quad*4+r4)*16 + l16] = acc[m][r4];
        __syncthreads();
        if (ew){
          const bool keep = (gld_e == 0);
          u32 gr[4] = {g0,g1,g2,g3};
          u32 hp=0, cp=0;
          #pragma unroll
          for (int i=0;i<2;++i){
            float gv[4];
            #pragma unroll
            for (int qq=0;qq<4;++qq)
              gv[qq] = gbuf[(qq*2+0)*512 + lb*16 + cdl+i]
                     + gbuf[(qq*2+1)*512 + lb*16 + cdl+i]
                     + bf2f((u16)(gr[qq] >> (16*i)));
            const float c1 = sigm(gv[1])*st0[i] + sigm(gv[0])*tanh_(gv[2]);
            const float h1 = sigm(gv[3])*tanh_(c1);
            st0[i] = keep ? c1 : 0.f;
            hp |= ((u32)f2bf(h1)) << (16*i);
            cp |= ((u32)f2bf(c1)) << (16*i);
          }
          astore32(Ucur + (long)eb*2304 + col, hp);
          astore32(Ucur + (long)eb*2304 + H_ + col, cp);
        }
      }
    } else {
      if (r >= 1){
        const u16* urow = Uprev + (long)sb0*2304;
        // ---- MLP staging: issue chunks 0+1, wait once, write; chunk2 overlaps
        u32x4 c0[6], c1[6], c2[6];
        llc_load96_nw(urow + scl0,       c0[0],c0[1],c0[2],c0[3],c0[4],c0[5]);
        llc_load96_nw(urow + 768 + scl0, c1[0],c1[1],c1[2],c1[3],c1[4],c1[5]);
        vmwait0();
        wr48(&ab[0][srw0*776 + scl0], c0);
        wr48(&ab[1][srw0*776 + scl0], c1);
        __syncthreads();
        llc_load96_nw(urow + 1536 + scl0, c2[0],c2[1],c2[2],c2[3],c2[4],c2[5]);
        f32x4 acc[2];
        acc[0] = (f32x4){0.f,0.f,0.f,0.f}; acc[1] = acc[0];
        #pragma unroll
        for (int kk=0;kk<12;++kk)
          #pragma unroll
          for (int m=0;m<2;++m){
            bf16x8 a = *(const bf16x8*)&ab[0][(m*16+l16)*776 + kh*384 + kk*32 + quad*8];
            acc[m] = mfma16(a, wfr[kk], acc[m]);
          }
        #pragma unroll
        for (int kk=0;kk<12;++kk)
          #pragma unroll
          for (int m=0;m<2;++m){
            bf16x8 a = *(const bf16x8*)&ab[1][(m*16+l16)*776 + kh*384 + kk*32 + quad*8];
            acc[m] = mfma16(a, wfr[12+kk], acc[m]);
          }
        vmwait0();
        wr48(&ab[2][srw0*776 + scl0], c2);
        __syncthreads();
        #pragma unroll
        for (int kk=0;kk<12;++kk)
          #pragma unroll
          for (int m=0;m<2;++m){
            bf16x8 a = *(const bf16x8*)&ab[2][(m*16+l16)*776 + kh*384 + kk*32 + quad*8];
            acc[m] = mfma16(a, wfr[24+kk], acc[m]);
          }
        __syncthreads();
        #pragma unroll
        for (int m=0;m<2;++m)
          #pragma unroll
          for (int r4=0;r4<4;++r4)
            gbuf[(q*2+kh)*512 + (m*16+quad*4+r4)*16 + l16] = acc[m][r4];
        __syncthreads();
        if (ew){
          const bool keep = (gld == 0);
          const int tp = r - 1;
          float p0 = 0.f, p1 = 0.f;
          u32 wp = 0;
          #pragma unroll
          for (int i=0;i<2;++i){
            float gv[4];
            #pragma unroll
            for (int qq=0;qq<4;++qq)
              gv[qq] = gbuf[(qq*2+0)*512 + lb*16 + cdl+i]
                     + gbuf[(qq*2+1)*512 + lb*16 + cdl+i]
                     + wbv[qq][i];
            const float wc1 = sigm(gv[1])*st1[i] + sigm(gv[0])*tanh_(gv[2]);
            const float wh1 = sigm(gv[3])*tanh_(wc1);
            st1[i] = keep ? st1[i] : wc1;
            st2[i] = keep ? st2[i] : wh1;
            p0 += wh1 * clv[0][i];
            p1 += wh1 * clv[1][i];
            wp |= ((u32)f2bf(st2[i])) << (16*i);
          }
          astore32(Ucur + (long)eb*2304 + D2_ + col, wp);
          p0 += __shfl_xor(p0, 1); p0 += __shfl_xor(p0, 2); p0 += __shfl_xor(p0, 4);
          p1 += __shfl_xor(p1, 1); p1 += __shfl_xor(p1, 2); p1 += __shfl_xor(p1, 4);
          if ((tid & 7) == 0){
            float* pp = partials + ((long)(tp*48 + s)*64 + eb)*2;
            pp[0] = p0; pp[1] = p1;
          }
        }
      }
    }
    // ---- release own flag (256B stride, relaxed) ----
    __threadfence_block();
    __syncthreads();
    if (tid == 0)
      __hip_atomic_store(&flags[(grp*48 + s)*64], r+1, __ATOMIC_RELAXED, __HIP_MEMORY_SCOPE_AGENT);
  }
  if (ew){
    if (role == 0){
      scS[eb*H_+col] = st0[0]; scS[eb*H_+col+1] = st0[1];
    } else {
      wcS[eb*H_+col] = st1[0]; wcS[eb*H_+col+1] = st1[1];
      whS[eb*H_+col] = st2[0]; whS[eb*H_+col+1] = st2[1];
    }
  }
}

// ---------------- classifier epilogue: out = first | cls_b + wh-part + x-part --
__global__ __launch_bounds__(256) void k_cls(
    const u16* __restrict__ lstm, const float* __restrict__ partials,
    const float* __restrict__ clsW, const float* __restrict__ clsb,
    float* __restrict__ out)
{
  const int ts = blockIdx.x;
  const int b  = blockIdx.y;
  const int tid = threadIdx.x;
  if (ts == 0) {
    if (tid == 0) { out[(long)b*S_*2 + 0] = -1.f; out[(long)b*S_*2 + 1] = 1.f; }
    return;
  }
  const int t = ts - 1;
  float s0 = 0.f, s1 = 0.f;
  const u16* xr = lstm + ((long)b*S_ + ts)*D2_;
  for (int k = tid; k < D2_; k += 256) {
    const float xv = bf2f(xr[k]);
    s0 += xv * clsW[768 + k];
    s1 += xv * clsW[2304 + 768 + k];
  }
  if (tid < 48) {
    const float* pr = partials + ((long)(t*48 + tid)*64 + b)*2;
    s0 += pr[0]; s1 += pr[1];
  }
  __shared__ float r0[256], r1[256];
  r0[tid] = s0; r1[tid] = s1; __syncthreads();
  for (int off = 128; off > 0; off >>= 1) {
    if (tid < off) { r0[tid] += r0[tid+off]; r1[tid] += r1[tid+off]; }
    __syncthreads();
  }
  if (tid == 0) {
    out[((long)b*S_ + ts)*2 + 0] = r0[0] + clsb[0];
    out[((long)b*S_ + ts)*2 + 1] = r1[0] + clsb[1];
  }
}

extern "C" void kernel_launch(void* const* d_in, const int* in_sizes, int n_in,
                              void* d_out, int out_size, void* d_ws, size_t ws_size,
                              hipStream_t stream)
{
  (void)in_sizes; (void)n_in; (void)out_size; (void)ws_size;
  const float* x     = (const float*)d_in[0];
  const int*   golds = (const int*)d_in[1];
  const float* wihf  = (const float*)d_in[2];
  const float* whhf  = (const float*)d_in[3];
  const float* bfw   = (const float*)d_in[4];
  const float* wihb  = (const float*)d_in[5];
  const float* whhb  = (const float*)d_in[6];
  const float* bbw   = (const float*)d_in[7];
  const float* swih  = (const float*)d_in[8];
  const float* swhh  = (const float*)d_in[9];
  const float* sb    = (const float*)d_in[10];
  const float* wwih  = (const float*)d_in[11];
  const float* wwhh  = (const float*)d_in[12];
  const float* wb    = (const float*)d_in[13];
  const float* clsW  = (const float*)d_in[14];
  const float* clsb  = (const float*)d_in[15];
  float* out = (float*)d_out;

  char* base = (char*)d_ws;
  // -------- zero-init region (memset each launch) ------------------------------
  u16*   h0   = (u16*)(base + 0);            // zeros during bilstm (1.18MB region)
  int*   flg2 = (int*)(base + 1179648);      // bilstm flags: 192 slots * 256 B
  int*   flg4 = (int*)(base + 1228800);      // decode flags
  float* cstf = (float*)(base + 1277952);    // bilstm fwd c-state 64x768 f32
  float* cstb = (float*)(base + 1474560);
  float* scS  = (float*)(base + 1671168);    // decode subword c
  float* wcS  = (float*)(base + 1867776);    // decode word c
  float* whS  = (float*)(base + 2064384);    // decode word h
  // zero region ends at 2,260,992
  // -------- scratch (fully written before read) --------------------------------
  u16* xb     = (u16*)(base + 2260992);
  u16* wihf_b = (u16*)(base + 27426816);
  u16* whhf_b = (u16*)(base + 32145408);
  u16* wihb_b = (u16*)(base + 36864000);
  u16* whhb_b = (u16*)(base + 41582592);
  u16* swih_b = (u16*)(base + 46301184);     // 3072x1536
  u16* swhh_b = (u16*)(base + 55738368);     // 3072x768
  u16* wwrd_b = (u16*)(base + 60456960);     // packed [word_Wih | word_Whh] 3072x2304
  u16* Gfseg  = (u16*)(base + 74612736);     // 4096x3072 bf16 segment
  u16* Gbseg  = (u16*)(base + 99778560);
  u16* lstm   = (u16*)(base + 124944384);    // (B,S,1536) bf16
  // total footprint: 175,276,032 B (unchanged)
  u16* Gsubseg = Gfseg;
  float* prt   = (float*)Gbseg;              // partials: 6.27MB at Gbseg+0 (decode)
  // 8-deep U ring (2.36MB) lives in dead Gbseg scratch after partials;
  // zeroed by a second memset between the bilstm and decode phases.
  u16* U       = (u16*)(base + 99778560 + 8388608);   // Gbseg + 8MB

  hipMemsetAsync(d_ws, 0, 2260992, stream);

  k_conv<<<16384, 256, 0, stream>>>(x,    xb,     768,  768,  768);
  k_conv<<<3072,  256, 0, stream>>>(wihf, wihf_b, 768,  768,  768);
  k_conv<<<3072,  256, 0, stream>>>(whhf, whhf_b, 768,  768,  768);
  k_conv<<<3072,  256, 0, stream>>>(wihb, wihb_b, 768,  768,  768);
  k_conv<<<3072,  256, 0, stream>>>(whhb, whhb_b, 768,  768,  768);
  k_conv<<<3072,  256, 0, stream>>>(swih, swih_b, 1536, 1536, 1536);
  k_conv<<<3072,  256, 0, stream>>>(swhh, swhh_b, 768,  768,  768);
  k_conv<<<3072,  256, 0, stream>>>(wwih, wwrd_b,        1536, 1536, 2304);
  k_conv<<<3072,  256, 0, stream>>>(wwhh, wwrd_b + 1536, 768,  768,  2304);

  dim3 gg(24, 32);
  for (int sgi = 0; sgi < 4; ++sgi) {
    const int t0f = sgi*SEG;
    const int tb0 = (3 - sgi)*SEG;
    k_gemm<<<gg, 256, 0, stream>>>(xb, wihf_b, bfw, Gfseg, 768, t0f);
    k_gemm<<<gg, 256, 0, stream>>>(xb, wihb_b, bbw, Gbseg, 768, tb0);
    k_bilstm<<<192, 512, 0, stream>>>(Gfseg, Gbseg, whhf_b, whhb_b, h0, lstm,
                                      cstf, cstb, flg2, t0f, tb0, sgi*SEG);
  }

  // zero the 8-deep U ring (Gbseg scratch was clobbered by bilstm-phase gemms)
  hipMemsetAsync(U, 0, 8*USZ*2, stream);

  for (int sgi = 0; sgi < 4; ++sgi) {
    const int r0 = sgi*SEG;
    k_gemm<<<gg, 256, 0, stream>>>(lstm, swih_b, sb, Gsubseg, 1536, r0);
    k_decode<<<192, 512, 0, stream>>>(Gsubseg, swhh_b, wwrd_b, wb, clsW, golds,
                                      U, scS, wcS, whS, prt, flg4, r0);
  }

  dim3 gc(256, 64);
  k_cls<<<gc, 256, 0, stream>>>(lstm, prt, clsW, clsb, out);
}

// Round 8
// 4070.087 us; speedup vs baseline: 1.0218x; 1.0150x over previous
//
#include <hip/hip_runtime.h>

#define B_  64
#define S_  256
#define H_  768
#define H4_ 3072
#define D2_ 1536
#define SEG 64
#define USZ (64*2304)

using u16 = unsigned short;
using u32 = unsigned int;
using u64 = unsigned long long;
typedef __attribute__((ext_vector_type(8))) short bf16x8;
typedef __attribute__((ext_vector_type(4))) float f32x4;
typedef __attribute__((ext_vector_type(4))) unsigned int u32x4;

#define DEV __device__ __forceinline__

DEV float bf2f(u16 u){ union{u32 i; float f;} c; c.i = ((u32)u)<<16; return c.f; }
DEV u16 f2bf(float f){ union{float f; u32 i;} c; c.f = f; return (u16)((c.i + 0x7FFFu + ((c.i>>16)&1u)) >> 16); }
DEV float sigm(float x){ return 1.f/(1.f + __expf(-x)); }
DEV float tanh_(float x){ return 2.f/(1.f + __expf(-2.f*x)) - 1.f; }

// agent-scope publication / flag ops
DEV void astore32(u16* p, u32 v){ __hip_atomic_store((u32*)p, v, __ATOMIC_RELAXED, __HIP_MEMORY_SCOPE_AGENT); }
DEV int afload(const int* p){ return __hip_atomic_load(p, __ATOMIC_RELAXED, __HIP_MEMORY_SCOPE_AGENT); }

DEV f32x4 mfma16(bf16x8 a, bf16x8 b, f32x4 c){
  return __builtin_amdgcn_mfma_f32_16x16x32_bf16(a, b, c, 0, 0, 0);
}

// 96B (48 u16) coherent staging load: 6 x dwordx4 bypassing L1/L2 (sc0 sc1 ->
// LLC-direct), one vmcnt drain.
DEV void llc_load96(const u16* p, u32x4& a0, u32x4& a1, u32x4& a2,
                    u32x4& a3, u32x4& a4, u32x4& a5){
  asm volatile(
    "global_load_dwordx4 %0, %6, off sc0 sc1\n\t"
    "global_load_dwordx4 %1, %6, off offset:16 sc0 sc1\n\t"
    "global_load_dwordx4 %2, %6, off offset:32 sc0 sc1\n\t"
    "global_load_dwordx4 %3, %6, off offset:48 sc0 sc1\n\t"
    "global_load_dwordx4 %4, %6, off offset:64 sc0 sc1\n\t"
    "global_load_dwordx4 %5, %6, off offset:80 sc0 sc1\n\t"
    "s_waitcnt vmcnt(0)"
    : "=&v"(a0), "=&v"(a1), "=&v"(a2), "=&v"(a3), "=&v"(a4), "=&v"(a5)
    : "v"(p));
}
// non-waiting variant: issue only; caller must vmwait0() before consuming.
DEV void llc_load96_nw(const u16* p, u32x4& a0, u32x4& a1, u32x4& a2,
                       u32x4& a3, u32x4& a4, u32x4& a5){
  asm volatile(
    "global_load_dwordx4 %0, %6, off sc0 sc1\n\t"
    "global_load_dwordx4 %1, %6, off offset:16 sc0 sc1\n\t"
    "global_load_dwordx4 %2, %6, off offset:32 sc0 sc1\n\t"
    "global_load_dwordx4 %3, %6, off offset:48 sc0 sc1\n\t"
    "global_load_dwordx4 %4, %6, off offset:64 sc0 sc1\n\t"
    "global_load_dwordx4 %5, %6, off offset:80 sc0 sc1"
    : "=&v"(a0), "=&v"(a1), "=&v"(a2), "=&v"(a3), "=&v"(a4), "=&v"(a5)
    : "v"(p));
}
DEV void vmwait0(){ asm volatile("s_waitcnt vmcnt(0)" ::: "memory"); }

DEV void stage48llc(u16* dst, const u16* src){
  u32x4 a0,a1,a2,a3,a4,a5;
  llc_load96(src, a0,a1,a2,a3,a4,a5);
  *(u32x4*)(dst)    = a0; *(u32x4*)(dst+8)  = a1;
  *(u32x4*)(dst+16) = a2; *(u32x4*)(dst+24) = a3;
  *(u32x4*)(dst+32) = a4; *(u32x4*)(dst+40) = a5;
}
DEV void stage48llcz(u16* dst, const u16* src, bool keep){
  u32x4 a0,a1,a2,a3,a4,a5;
  llc_load96(src, a0,a1,a2,a3,a4,a5);
  const u32x4 z = {0u,0u,0u,0u};
  if (!keep){ a0=z; a1=z; a2=z; a3=z; a4=z; a5=z; }
  *(u32x4*)(dst)    = a0; *(u32x4*)(dst+8)  = a1;
  *(u32x4*)(dst+16) = a2; *(u32x4*)(dst+24) = a3;
  *(u32x4*)(dst+32) = a4; *(u32x4*)(dst+40) = a5;
}
DEV void wr48(u16* dst, const u32x4* a){
  *(u32x4*)(dst)    = a[0]; *(u32x4*)(dst+8)  = a[1];
  *(u32x4*)(dst+16) = a[2]; *(u32x4*)(dst+24) = a[3];
  *(u32x4*)(dst+32) = a[4]; *(u32x4*)(dst+40) = a[5];
}

// ---------------- fp32 -> bf16 convert (strided dst for packing) ---------------
__global__ void k_conv(const float* __restrict__ src, u16* __restrict__ dst,
                       int cols, int sld, int dld){
  const long r = blockIdx.x;
  for (int c = threadIdx.x*4; c < cols; c += 1024) {
    const float* sp = src + r*sld + c;
    float a = sp[0], b = sp[1], cc = sp[2], d = sp[3];
    u64 pack = (u64)f2bf(a) | ((u64)f2bf(b)<<16) | ((u64)f2bf(cc)<<32) | ((u64)f2bf(d)<<48);
    *(u64*)(dst + r*dld + c) = pack;
  }
}

// ---- C(bf16, 4096x3072) = A[b,t0+tt](bf16) @ W(bf16)^T + bias, 128x128 tile ---
__global__ __launch_bounds__(256) void k_gemm(
    const u16* __restrict__ A, const u16* __restrict__ W,
    const float* __restrict__ bias, u16* __restrict__ C, int K, int t0)
{
  __shared__ u16 at[128*40];
  __shared__ u16 bt[128*40];
  const int tid = threadIdx.x;
  const int L = tid & 63, wv = tid >> 6;
  const int mq = wv >> 1, nq = wv & 1;
  const int l16 = L & 15, quad = L >> 4;
  const long mb = blockIdx.y, nb = blockIdx.x;

  f32x4 acc[4][4];
  #pragma unroll
  for (int m=0;m<4;++m)
    #pragma unroll
    for (int n=0;n<4;++n)
      acc[m][n] = (f32x4){0.f,0.f,0.f,0.f};

  const int r = tid >> 1, c0 = (tid & 1) * 16;
  const int fr = (int)mb*128 + r;
  const long arow = ((long)(fr >> 6))*S_ + t0 + (fr & 63);
  const u16* Arow = A + arow*(long)K + c0;
  const u16* Wrow = W + (nb*128 + r)*(long)K + c0;

  for (int kb = 0; kb < K; kb += 32) {
    *(u32x4*)&at[r*40 + c0]     = *(const u32x4*)(Arow + kb);
    *(u32x4*)&at[r*40 + c0 + 8] = *(const u32x4*)(Arow + kb + 8);
    *(u32x4*)&bt[r*40 + c0]     = *(const u32x4*)(Wrow + kb);
    *(u32x4*)&bt[r*40 + c0 + 8] = *(const u32x4*)(Wrow + kb + 8);
    __syncthreads();
    bf16x8 af[4], bfr[4];
    #pragma unroll
    for (int m=0;m<4;++m) af[m]  = *(const bf16x8*)&at[(mq*64 + m*16 + l16)*40 + quad*8];
    #pragma unroll
    for (int n=0;n<4;++n) bfr[n] = *(const bf16x8*)&bt[(nq*64 + n*16 + l16)*40 + quad*8];
    #pragma unroll
    for (int m=0;m<4;++m)
      #pragma unroll
      for (int n=0;n<4;++n)
        acc[m][n] = mfma16(af[m], bfr[n], acc[m][n]);
    __syncthreads();
  }
  #pragma unroll
  for (int n=0;n<4;++n) {
    const long col = nb*128 + nq*64 + n*16 + l16;
    const float bv = bias[col];
    #pragma unroll
    for (int m=0;m<4;++m) {
      const long row0 = mb*128 + mq*64 + m*16 + quad*4;
      #pragma unroll
      for (int rr=0;rr<4;++rr)
        C[(row0+rr)*3072 + col] = f2bf(acc[m][n][rr] + bv);
    }
  }
}

// ------- persistent bilstm segment: 192 wgs = 2 dirs x 2 bhalf x 48 slices -----
// 512 thr = 8 waves = gate q(4) x k-half kh(2); weights persistent in VGPRs.
// Monolithic full-width staging via LLC-direct 16B loads. Flags 256B stride,
// RELAXED store (RELEASE's implied L2 writeback walk cost ~2ms total).
__global__ __launch_bounds__(512,2) void k_bilstm(
    const u16* __restrict__ Gf, const u16* __restrict__ Gb,
    const u16* __restrict__ Whhf, const u16* __restrict__ Whhb,
    const u16* __restrict__ h0, u16* __restrict__ lstm,
    float* __restrict__ cstf, float* __restrict__ cstb,
    int* __restrict__ flags, int t0f, int tb0, int ep0)
{
  __shared__ __align__(16) u16 lds[32*776];   // staged 32x768 (+8 pad)
  float* gbuf = (float*)lds;                  // 16KB alias (post-MFMA)
  const int wg = blockIdx.x;
  const int dir = wg / 96, rem = wg % 96, mh = rem / 48, s = rem % 48;
  const int grp = dir*2 + mh;
  const int tid = threadIdx.x;
  const int wave = tid >> 6, q = wave & 3, kh = wave >> 2;
  const int L = tid & 63, l16 = L & 15, quad = L >> 4;
  const int srw = tid >> 4, scl = (tid & 15) * 48;   // 32 rows x 16 chunks

  const u16* Gsrc = dir ? Gb : Gf;
  const u16* W    = dir ? Whhb : Whhf;
  float* cst      = dir ? cstb : cstf;

  bf16x8 bfr[12];
  {
    const u16* wr = W + (long)(q*H_ + s*16 + l16)*H_ + kh*384 + quad*8;
    #pragma unroll
    for (int kk=0;kk<12;++kk) bfr[kk] = *(const bf16x8*)(wr + kk*32);
  }

  const int lb = tid >> 3, cdl = (tid & 7) * 2;
  const int eb = mh*32 + lb, col = s*16 + cdl;
  const bool ew = (tid < 256);
  float creg[2] = {0.f, 0.f};
  if (ew){ creg[0] = cst[eb*H_ + col]; creg[1] = cst[eb*H_ + col + 1]; }

  u32 g0=0,g1=0,g2=0,g3=0;
  if (ew){
    const int tp0 = dir ? (tb0 + SEG-1) : t0f;
    const int gidx = eb*SEG + (dir ? (tp0 - tb0) : (tp0 - t0f));
    const u16* grow = Gsrc + (long)gidx*H4_ + col;
    g0 = *(const u32*)(grow);      g1 = *(const u32*)(grow + H_);
    g2 = *(const u32*)(grow+2*H_); g3 = *(const u32*)(grow+3*H_);
  }

  for (int t=0; t<SEG; ++t) {
    const int tp = dir ? (tb0 + SEG-1 - t) : (t0f + t);
    const bool first = dir ? (tp == S_-1) : (tp == 0);
    const u16* hbase; long ldh;
    if (first){ hbase = h0 + dir*H_; ldh = D2_; }
    else {
      const int tprev = dir ? (tp+1) : (tp-1);
      hbase = lstm + (long)tprev*D2_ + dir*H_;
      ldh = (long)S_*D2_;
    }
    // monolithic stage 32x768 by all 512 threads
    stage48llc(&lds[srw*776 + scl], hbase + (long)(mh*32 + srw)*ldh + scl);
    __syncthreads();
    f32x4 acc[2];
    acc[0] = (f32x4){0.f,0.f,0.f,0.f}; acc[1] = acc[0];
    #pragma unroll
    for (int kk=0;kk<12;++kk)
      #pragma unroll
      for (int m=0;m<2;++m){
        bf16x8 a = *(const bf16x8*)&lds[(m*16+l16)*776 + kh*384 + kk*32 + quad*8];
        acc[m] = mfma16(a, bfr[kk], acc[m]);
      }
    __syncthreads();
    #pragma unroll
    for (int m=0;m<2;++m)
      #pragma unroll
      for (int rr=0;rr<4;++rr)
        gbuf[(q*2+kh)*512 + (m*16+quad*4+rr)*16 + l16] = acc[m][rr];
    __syncthreads();
    if (ew){
      u32 gr[4] = {g0,g1,g2,g3};
      u32 hp = 0;
      #pragma unroll
      for (int i=0;i<2;++i){
        float gv[4];
        #pragma unroll
        for (int qq=0;qq<4;++qq)
          gv[qq] = gbuf[(qq*2+0)*512 + lb*16 + cdl+i]
                 + gbuf[(qq*2+1)*512 + lb*16 + cdl+i]
                 + bf2f((u16)(gr[qq] >> (16*i)));
        const float c = sigm(gv[1])*creg[i] + sigm(gv[0])*tanh_(gv[2]);
        creg[i] = c;
        const float h = sigm(gv[3])*tanh_(c);
        hp |= ((u32)f2bf(h)) << (16*i);
      }
      astore32(lstm + ((long)eb*S_ + tp)*D2_ + dir*H_ + col, hp);
    }
    // ---- release first (fence only drains the h-store), then prefetch, poll ---
    __threadfence_block();
    __syncthreads();
    if (tid == 0)
      __hip_atomic_store(&flags[(grp*48 + s)*64], ep0 + t + 1, __ATOMIC_RELAXED, __HIP_MEMORY_SCOPE_AGENT);
    if (ew){
      // next round's G prefetch overlaps the poll (last-t value unused)
      const int t2 = t + 1;
      const int tp2 = dir ? (tb0 + SEG-1 - t2) : (t0f + t2);
      const long gidx2 = (long)eb*SEG + (dir ? (tp2 - tb0) : (tp2 - t0f));
      const u16* grow2 = Gsrc + gidx2*H4_ + col;
      g0 = *(const u32*)(grow2);      g1 = *(const u32*)(grow2 + H_);
      g2 = *(const u32*)(grow2+2*H_); g3 = *(const u32*)(grow2+3*H_);
    }
    if ((int)tid < 48) {
      while (afload(&flags[(grp*48 + (int)tid)*64]) < ep0 + t + 1)
        __builtin_amdgcn_s_sleep(1);
    }
    __syncthreads();
  }
  if (ew){ cst[eb*H_ + col] = creg[0]; cst[eb*H_ + col + 1] = creg[1]; }
}

// -------- persistent decode: 192 wgs = role(sub/word) x 2 bhalf x 48 slices ----
// role0 computes subword(t=r); role1 computes word(t=r-1). 64-DEEP U ring in
// dead xb scratch (slot = r&63, unique per dispatch): clobber guard relaxes to
// r-56 (role1 fully off role0's cycle; guard is a never-binding safety net).
// role1 PUBLISH-EARLY: wh store -> fence -> flag; classifier partials (shfl +
// stores, no consumer until k_cls) moved AFTER the flag -> off the chain.
__global__ __launch_bounds__(512,1) void k_decode(
    const u16* __restrict__ Gsub, const u16* __restrict__ Wsub,
    const u16* __restrict__ Wwrd, const float* __restrict__ wbias,
    const float* __restrict__ clsW, const int* __restrict__ golds,
    u16* __restrict__ U,
    float* __restrict__ scS, float* __restrict__ wcS, float* __restrict__ whS,
    float* __restrict__ partials, int* __restrict__ flags, int r0)
{
  __shared__ __align__(16) u16 ab[3][32*776];   // role1: 3 chunk buffers; role0: ab[0]
  float* gbuf = (float*)ab;
  const int wg = blockIdx.x;
  const int role = wg / 96, rem = wg % 96, mh = rem / 48, s = rem % 48;
  const int grp = role*2 + mh;
  const int tid = threadIdx.x;
  const int wave = tid >> 6, q = wave & 3, kh = wave >> 2;
  const int L = tid & 63, l16 = L & 15, quad = L >> 4;
  const int srw0 = tid >> 4, scl0 = (tid & 15) * 48;   // 512-thread stage map
  const int lb = tid >> 3, cdl = (tid & 7)*2;
  const int eb = mh*32 + lb, col = s*16 + cdl;
  const bool ew = (tid < 256);
  const int sb0 = mh*32 + srw0;   // staged row (batch)
  u16* abf = &ab[0][0];           // role0 flat buffer, stride 776

  bf16x8 wfr[36];
  float st0[2] = {0.f,0.f}, st1[2] = {0.f,0.f}, st2[2] = {0.f,0.f};
  float wbv[4][2], clv[2][2];
  if (role == 0){
    const u16* wr = Wsub + (long)(q*H_ + s*16 + l16)*H_ + kh*384 + quad*8;
    #pragma unroll
    for (int kk=0;kk<12;++kk) wfr[kk] = *(const bf16x8*)(wr + kk*32);
    if (ew){ st0[0] = scS[eb*H_+col]; st0[1] = scS[eb*H_+col+1]; }
  } else {
    const u16* wr = Wwrd + (long)(q*H_ + s*16 + l16)*2304 + kh*384 + quad*8;
    #pragma unroll
    for (int cc=0;cc<3;++cc)
      #pragma unroll
      for (int kk=0;kk<12;++kk)
        wfr[cc*12+kk] = *(const bf16x8*)(wr + cc*768 + kk*32);
    if (ew){
      st1[0] = wcS[eb*H_+col]; st1[1] = wcS[eb*H_+col+1];
      st2[0] = whS[eb*H_+col]; st2[1] = whS[eb*H_+col+1];
      #pragma unroll
      for (int qq=0;qq<4;++qq){ wbv[qq][0]=wbias[qq*H_+col]; wbv[qq][1]=wbias[qq*H_+col+1]; }
      clv[0][0]=clsW[col]; clv[0][1]=clsW[col+1];
      clv[1][0]=clsW[2304+col]; clv[1][1]=clsW[2304+col+1];
    }
  }

  int stg_g = golds[sb0*S_ + ((r0 < 255) ? r0 : 255)];   // staging mask carry (role0)

  for (int rr=0; rr<SEG; ++rr){
    const int r = r0 + rr;
    // ---- flag-independent loads issued BEFORE the wait (latency hides) ----
    u32 g0=0,g1=0,g2=0,g3=0; int gld_e = 0, gld = 0;
    if (ew){
      if (role == 0 && r <= 254){
        gld_e = golds[eb*S_ + r + 1];
        const u16* grow = Gsub + ((long)eb*SEG + rr)*H4_ + col;
        g0 = *(const u32*)(grow);      g1 = *(const u32*)(grow + H_);
        g2 = *(const u32*)(grow+2*H_); g3 = *(const u32*)(grow+3*H_);
      } else if (role == 1 && r >= 1){
        gld = golds[eb*S_ + r];
      }
    }
    // ---- decoupled 48-wide waits (256B-strided flags) ----
    if (tid < 96){
      int idx, tgt;
      if (tid < 48){ idx = mh*48 + tid; tgt = r; }
      else { idx = (2+mh)*48 + (tid-48); tgt = (role==0) ? (r-56) : r; }
      while (afload(&flags[idx*64]) < tgt) __builtin_amdgcn_s_sleep(1);
    }
    __syncthreads();

    const u16* Uprev = U + (long)((r+63)&63)*USZ;
    u16*       Ucur  = U + (long)(r&63)*USZ;

    // role1 deferred-epilogue state (computed pre-publish, stored post-publish)
    float p0 = 0.f, p1 = 0.f; bool do_part = false; int tp = 0;

    if (role == 0){
      if (r <= 254){
        const bool keep_s = (r > 0) && (stg_g == 0);
        // monolithic 512-thread stage of the full 32x768 h1 block
        stage48llcz(&abf[srw0*776 + scl0], Uprev + (long)sb0*2304 + scl0, keep_s);
        __syncthreads();
        f32x4 acc[2];
        acc[0] = (f32x4){0.f,0.f,0.f,0.f}; acc[1] = acc[0];
        #pragma unroll
        for (int kk=0;kk<12;++kk)
          #pragma unroll
          for (int m=0;m<2;++m){
            bf16x8 a = *(const bf16x8*)&abf[(m*16+l16)*776 + kh*384 + kk*32 + quad*8];
            acc[m] = mfma16(a, wfr[kk], acc[m]);
          }
        __syncthreads();
        stg_g = golds[sb0*S_ + ((r+1 < 255) ? r+1 : 255)];
        #pragma unroll
        for (int m=0;m<2;++m)
          #pragma unroll
          for (int r4=0;r4<4;++r4)
            gbuf[(q*2+kh)*512 + (m*16+quad*4+r4)*16 + l16] = acc[m][r4];
        __syncthreads();
        if (ew){
          const bool keep = (gld_e == 0);
          u32 gr[4] = {g0,g1,g2,g3};
          u32 hp=0, cp=0;
          #pragma unroll
          for (int i=0;i<2;++i){
            float gv[4];
            #pragma unroll
            for (int qq=0;qq<4;++qq)
              gv[qq] = gbuf[(qq*2+0)*512 + lb*16 + cdl+i]
                     + gbuf[(qq*2+1)*512 + lb*16 + cdl+i]
                     + bf2f((u16)(gr[qq] >> (16*i)));
            const float c1 = sigm(gv[1])*st0[i] + sigm(gv[0])*tanh_(gv[2]);
            const float h1 = sigm(gv[3])*tanh_(c1);
            st0[i] = keep ? c1 : 0.f;
            hp |= ((u32)f2bf(h1)) << (16*i);
            cp |= ((u32)f2bf(c1)) << (16*i);
          }
          astore32(Ucur + (long)eb*2304 + col, hp);
          astore32(Ucur + (long)eb*2304 + H_ + col, cp);
        }
      }
    } else {
      if (r >= 1){
        const u16* urow = Uprev + (long)sb0*2304;
        // ---- MLP staging: issue chunks 0+1, wait once, write; chunk2 overlaps
        u32x4 c0[6], c1[6], c2[6];
        llc_load96_nw(urow + scl0,       c0[0],c0[1],c0[2],c0[3],c0[4],c0[5]);
        llc_load96_nw(urow + 768 + scl0, c1[0],c1[1],c1[2],c1[3],c1[4],c1[5]);
        vmwait0();
        wr48(&ab[0][srw0*776 + scl0], c0);
        wr48(&ab[1][srw0*776 + scl0], c1);
        __syncthreads();
        llc_load96_nw(urow + 1536 + scl0, c2[0],c2[1],c2[2],c2[3],c2[4],c2[5]);
        f32x4 acc[2];
        acc[0] = (f32x4){0.f,0.f,0.f,0.f}; acc[1] = acc[0];
        #pragma unroll
        for (int kk=0;kk<12;++kk)
          #pragma unroll
          for (int m=0;m<2;++m){
            bf16x8 a = *(const bf16x8*)&ab[0][(m*16+l16)*776 + kh*384 + kk*32 + quad*8];
            acc[m] = mfma16(a, wfr[kk], acc[m]);
          }
        #pragma unroll
        for (int kk=0;kk<12;++kk)
          #pragma unroll
          for (int m=0;m<2;++m){
            bf16x8 a = *(const bf16x8*)&ab[1][(m*16+l16)*776 + kh*384 + kk*32 + quad*8];
            acc[m] = mfma16(a, wfr[12+kk], acc[m]);
          }
        vmwait0();
        wr48(&ab[2][srw0*776 + scl0], c2);
        __syncthreads();
        #pragma unroll
        for (int kk=0;kk<12;++kk)
          #pragma unroll
          for (int m=0;m<2;++m){
            bf16x8 a = *(const bf16x8*)&ab[2][(m*16+l16)*776 + kh*384 + kk*32 + quad*8];
            acc[m] = mfma16(a, wfr[24+kk], acc[m]);
          }
        __syncthreads();
        #pragma unroll
        for (int m=0;m<2;++m)
          #pragma unroll
          for (int r4=0;r4<4;++r4)
            gbuf[(q*2+kh)*512 + (m*16+quad*4+r4)*16 + l16] = acc[m][r4];
        __syncthreads();
        if (ew){
          const bool keep = (gld == 0);
          tp = r - 1;
          u32 wp = 0;
          #pragma unroll
          for (int i=0;i<2;++i){
            float gv[4];
            #pragma unroll
            for (int qq=0;qq<4;++qq)
              gv[qq] = gbuf[(qq*2+0)*512 + lb*16 + cdl+i]
                     + gbuf[(qq*2+1)*512 + lb*16 + cdl+i]
                     + wbv[qq][i];
            const float wc1 = sigm(gv[1])*st1[i] + sigm(gv[0])*tanh_(gv[2]);
            const float wh1 = sigm(gv[3])*tanh_(wc1);
            st1[i] = keep ? st1[i] : wc1;
            st2[i] = keep ? st2[i] : wh1;
            p0 += wh1 * clv[0][i];
            p1 += wh1 * clv[1][i];
            wp |= ((u32)f2bf(st2[i])) << (16*i);
          }
          astore32(Ucur + (long)eb*2304 + D2_ + col, wp);
          do_part = true;
        }
      }
    }
    // ---- release own flag (256B stride, relaxed); only wh/h1/c1 precede it ----
    __threadfence_block();
    __syncthreads();
    if (tid == 0)
      __hip_atomic_store(&flags[(grp*48 + s)*64], r+1, __ATOMIC_RELAXED, __HIP_MEMORY_SCOPE_AGENT);
    // ---- deferred role1 classifier partials (consumed only by k_cls) ----------
    if (do_part){
      p0 += __shfl_xor(p0, 1); p0 += __shfl_xor(p0, 2); p0 += __shfl_xor(p0, 4);
      p1 += __shfl_xor(p1, 1); p1 += __shfl_xor(p1, 2); p1 += __shfl_xor(p1, 4);
      if ((tid & 7) == 0){
        float* pp = partials + ((long)(tp*48 + s)*64 + eb)*2;
        pp[0] = p0; pp[1] = p1;
      }
    }
  }
  if (ew){
    if (role == 0){
      scS[eb*H_+col] = st0[0]; scS[eb*H_+col+1] = st0[1];
    } else {
      wcS[eb*H_+col] = st1[0]; wcS[eb*H_+col+1] = st1[1];
      whS[eb*H_+col] = st2[0]; whS[eb*H_+col+1] = st2[1];
    }
  }
}

// ---------------- classifier epilogue: out = first | cls_b + wh-part + x-part --
__global__ __launch_bounds__(256) void k_cls(
    const u16* __restrict__ lstm, const float* __restrict__ partials,
    const float* __restrict__ clsW, const float* __restrict__ clsb,
    float* __restrict__ out)
{
  const int ts = blockIdx.x;
  const int b  = blockIdx.y;
  const int tid = threadIdx.x;
  if (ts == 0) {
    if (tid == 0) { out[(long)b*S_*2 + 0] = -1.f; out[(long)b*S_*2 + 1] = 1.f; }
    return;
  }
  const int t = ts - 1;
  float s0 = 0.f, s1 = 0.f;
  const u16* xr = lstm + ((long)b*S_ + ts)*D2_;
  for (int k = tid; k < D2_; k += 256) {
    const float xv = bf2f(xr[k]);
    s0 += xv * clsW[768 + k];
    s1 += xv * clsW[2304 + 768 + k];
  }
  if (tid < 48) {
    const float* pr = partials + ((long)(t*48 + tid)*64 + b)*2;
    s0 += pr[0]; s1 += pr[1];
  }
  __shared__ float r0[256], r1[256];
  r0[tid] = s0; r1[tid] = s1; __syncthreads();
  for (int off = 128; off > 0; off >>= 1) {
    if (tid < off) { r0[tid] += r0[tid+off]; r1[tid] += r1[tid+off]; }
    __syncthreads();
  }
  if (tid == 0) {
    out[((long)b*S_ + ts)*2 + 0] = r0[0] + clsb[0];
    out[((long)b*S_ + ts)*2 + 1] = r1[0] + clsb[1];
  }
}

extern "C" void kernel_launch(void* const* d_in, const int* in_sizes, int n_in,
                              void* d_out, int out_size, void* d_ws, size_t ws_size,
                              hipStream_t stream)
{
  (void)in_sizes; (void)n_in; (void)out_size; (void)ws_size;
  const float* x     = (const float*)d_in[0];
  const int*   golds = (const int*)d_in[1];
  const float* wihf  = (const float*)d_in[2];
  const float* whhf  = (const float*)d_in[3];
  const float* bfw   = (const float*)d_in[4];
  const float* wihb  = (const float*)d_in[5];
  const float* whhb  = (const float*)d_in[6];
  const float* bbw   = (const float*)d_in[7];
  const float* swih  = (const float*)d_in[8];
  const float* swhh  = (const float*)d_in[9];
  const float* sb    = (const float*)d_in[10];
  const float* wwih  = (const float*)d_in[11];
  const float* wwhh  = (const float*)d_in[12];
  const float* wb    = (const float*)d_in[13];
  const float* clsW  = (const float*)d_in[14];
  const float* clsb  = (const float*)d_in[15];
  float* out = (float*)d_out;

  char* base = (char*)d_ws;
  // -------- zero-init region (memset each launch) ------------------------------
  u16*   h0   = (u16*)(base + 0);            // zeros during bilstm (1.18MB region)
  int*   flg2 = (int*)(base + 1179648);      // bilstm flags: 192 slots * 256 B
  int*   flg4 = (int*)(base + 1228800);      // decode flags
  float* cstf = (float*)(base + 1277952);    // bilstm fwd c-state 64x768 f32
  float* cstb = (float*)(base + 1474560);
  float* scS  = (float*)(base + 1671168);    // decode subword c
  float* wcS  = (float*)(base + 1867776);    // decode word c
  float* whS  = (float*)(base + 2064384);    // decode word h
  // zero region ends at 2,260,992
  // -------- scratch (fully written before read) --------------------------------
  u16* xb     = (u16*)(base + 2260992);
  u16* wihf_b = (u16*)(base + 27426816);
  u16* whhf_b = (u16*)(base + 32145408);
  u16* wihb_b = (u16*)(base + 36864000);
  u16* whhb_b = (u16*)(base + 41582592);
  u16* swih_b = (u16*)(base + 46301184);     // 3072x1536
  u16* swhh_b = (u16*)(base + 55738368);     // 3072x768
  u16* wwrd_b = (u16*)(base + 60456960);     // packed [word_Wih | word_Whh] 3072x2304
  u16* Gfseg  = (u16*)(base + 74612736);     // 4096x3072 bf16 segment
  u16* Gbseg  = (u16*)(base + 99778560);
  u16* lstm   = (u16*)(base + 124944384);    // (B,S,1536) bf16
  // total footprint: 175,276,032 B (unchanged)
  u16* Gsubseg = Gfseg;
  float* prt   = (float*)Gbseg;              // partials: 6.27MB at Gbseg+0 (decode)
  // 64-deep U ring (18.87MB) lives in xb scratch — DEAD during the decode phase
  // (xb is only read by bilstm-phase gemms). Zeroed between phases.
  u16* U       = xb;

  hipMemsetAsync(d_ws, 0, 2260992, stream);

  k_conv<<<16384, 256, 0, stream>>>(x,    xb,     768,  768,  768);
  k_conv<<<3072,  256, 0, stream>>>(wihf, wihf_b, 768,  768,  768);
  k_conv<<<3072,  256, 0, stream>>>(whhf, whhf_b, 768,  768,  768);
  k_conv<<<3072,  256, 0, stream>>>(wihb, wihb_b, 768,  768,  768);
  k_conv<<<3072,  256, 0, stream>>>(whhb, whhb_b, 768,  768,  768);
  k_conv<<<3072,  256, 0, stream>>>(swih, swih_b, 1536, 1536, 1536);
  k_conv<<<3072,  256, 0, stream>>>(swhh, swhh_b, 768,  768,  768);
  k_conv<<<3072,  256, 0, stream>>>(wwih, wwrd_b,        1536, 1536, 2304);
  k_conv<<<3072,  256, 0, stream>>>(wwhh, wwrd_b + 1536, 768,  768,  2304);

  dim3 gg(24, 32);
  for (int sgi = 0; sgi < 4; ++sgi) {
    const int t0f = sgi*SEG;
    const int tb0 = (3 - sgi)*SEG;
    k_gemm<<<gg, 256, 0, stream>>>(xb, wihf_b, bfw, Gfseg, 768, t0f);
    k_gemm<<<gg, 256, 0, stream>>>(xb, wihb_b, bbw, Gbseg, 768, tb0);
    k_bilstm<<<192, 512, 0, stream>>>(Gfseg, Gbseg, whhf_b, whhb_b, h0, lstm,
                                      cstf, cstb, flg2, t0f, tb0, sgi*SEG);
  }

  // zero the 64-deep U ring (xb is dead from here on)
  hipMemsetAsync(U, 0, 64*(size_t)USZ*2, stream);

  for (int sgi = 0; sgi < 4; ++sgi) {
    const int r0 = sgi*SEG;
    k_gemm<<<gg, 256, 0, stream>>>(lstm, swih_b, sb, Gsubseg, 1536, r0);
    k_decode<<<192, 512, 0, stream>>>(Gsubseg, swhh_b, wwrd_b, wb, clsW, golds,
                                      U, scS, wcS, whS, prt, flg4, r0);
  }

  dim3 gc(256, 64);
  k_cls<<<gc, 256, 0, stream>>>(lstm, prt, clsW, clsb, out);
}